// Round 19
// baseline (90.959 us; speedup 1.0000x reference)
//
#include <hip/hip_runtime.h>
#include <hip/hip_fp16.h>

// DynamicGaussianBlur: [B=4, D=160, H=160, W=160, C=2] fp32, sigma [4,3],
// separable 3D gaussian, window 13 (radius 6), SAME zero padding.
// Two passes; ws is FP16 (half2 = channel pair):
//   A: D-blur register line-walk, float4-wide, depth-8 register prefetch
//      queue; INPUT loads NONTEMPORAL (don't allocate in L3 — input is
//      fill-trashed every replay anyway; keeps L3 for ws). in -> ws(fp16)
//   B: fused H+W blur per (b,d,h-tile); UNION LDS: fp16 slab (20,480 B)
//      for staging+H-blur, reused as f32 hbuf (27,520 B) for W-blur.
//      27.5 KB -> 5 blocks/CU. OUT stores nontemporal.    ws -> out

#define WSZ 13
#define RAD 6
#define SEGA 40       // pass A: d-segment per thread (5 chunks of 8)
#define NSEGA 4
#define CHK 8         // chunk size = prefetch depth

typedef float nfloat2 __attribute__((ext_vector_type(2)));   // nt-capable float2
typedef float nfloat4 __attribute__((ext_vector_type(4)));   // nt-capable float4

constexpr int BB = 4, DD = 160, HH = 160, WW = 160;
constexpr int R2 = 160;             // row in float2 / half2 units
constexpr int P2 = HH * WW;         // plane (25,600)
constexpr int N2 = DD * P2;         // batch volume
constexpr int P4 = P2 / 2;          // plane in float4 / uint2 units (12,800)
constexpr int N4 = N2 / 2;
constexpr int NCOL4 = BB * P4;      // pass-A float4 columns (51,200)

// Pass B tile
#define TB 20
#define SLABR (TB + 12)              // 32 slab rows (fp16: 20,480 B)
#define HBS 172                      // hbuf row stride (float2 units)
#define SMEM_BYTES (TB * HBS * 8)    // 27,520 B (f32 hbuf is the max)

__device__ __forceinline__ void make_weights(float sig, float* w) {
    const float invd = 1.0f / (2.0f * sig * sig + 1e-7f);
    float s = 0.0f;
#pragma unroll
    for (int k = 0; k < WSZ; ++k) {
        const float loc = (float)(k - RAD);
        w[k] = __expf(-loc * loc * invd);
        s += w[k];
    }
    const float inv = 1.0f / s;
#pragma unroll
    for (int k = 0; k < WSZ; ++k) w[k] *= inv;
}

__device__ __forceinline__ nfloat4 ldq_nt(const nfloat4* __restrict__ p, int ibase, int q) {
    nfloat4 v = (nfloat4)(0.0f);
    if (q >= 0 && q < DD) v = __builtin_nontemporal_load(&p[ibase + q * P4]);
    return v;
}

// ---------------- Pass A: D-blur walker, depth-8 prefetch, nt input reads ----------------
__global__ __launch_bounds__(256) void blur_d(const float2* __restrict__ in,
                                              __half2* __restrict__ ws,
                                              const float* __restrict__ sigma) {
    const nfloat4* in4 = (const nfloat4*)in;
    uint2* wsU = (uint2*)ws;

    const int cid = blockIdx.x * 256 + threadIdx.x;   // float4-column id
    const int b   = cid / P4;                         // uniform per block
    const int rem = cid % P4;

    float wgt[WSZ];
    make_weights(sigma[b * 3 + 0], wgt);

    const int ibase = b * N4 + rem;                   // float4 index at d=0
    const int obase = b * N4 + rem;                   // uint2 index at d=0
    const int p0 = blockIdx.y * SEGA;

    // win[0..12] = q = p0-7 .. p0+5  (win[0] is dropped before first use)
    nfloat4 win[WSZ];
    win[0] = (nfloat4)(0.0f);
#pragma unroll
    for (int k = 1; k < WSZ; ++k) win[k] = ldq_nt(in4, ibase, p0 - 7 + k);

    // nxt[0..7] = q = p0+6 .. p0+13
    nfloat4 nxt[CHK];
#pragma unroll
    for (int j = 0; j < CHK; ++j) nxt[j] = ldq_nt(in4, ibase, p0 + 6 + j);

#pragma unroll
    for (int t = 0; t < SEGA / CHK; ++t) {            // 5 chunks
        const int i0 = p0 + t * CHK;

        // issue next chunk's slide-in loads early: q = i0+14 .. i0+21
        nfloat4 fut[CHK];
        if (t + 1 < SEGA / CHK) {
#pragma unroll
            for (int j = 0; j < CHK; ++j) fut[j] = ldq_nt(in4, ibase, i0 + 14 + j);
        }

        // compute 8 outputs from win + nxt (loads issued one chunk ago)
#pragma unroll
        for (int j = 0; j < CHK; ++j) {
#pragma unroll
            for (int k = 0; k < WSZ - 1; ++k) win[k] = win[k + 1];
            win[WSZ - 1] = nxt[j];

            float a0 = 0.f, a1 = 0.f, a2 = 0.f, a3 = 0.f;
#pragma unroll
            for (int k = 0; k < WSZ; ++k) {
                const nfloat4 v = win[k];
                a0 += wgt[k] * v.x; a1 += wgt[k] * v.y;
                a2 += wgt[k] * v.z; a3 += wgt[k] * v.w;
            }
            union { uint2 u; __half2 h[2]; } o;
            o.h[0] = __float22half2_rn(make_float2(a0, a1));
            o.h[1] = __float22half2_rn(make_float2(a2, a3));
            wsU[obase + (i0 + j) * P4] = o.u;         // normal store: keep ws in L3
        }

        if (t + 1 < SEGA / CHK) {
#pragma unroll
            for (int j = 0; j < CHK; ++j) nxt[j] = fut[j];
        }
    }
}

// ---------------- Pass B: fused H+W blur, union LDS, one (b,d,h-tile) per block ----------------
__global__ __launch_bounds__(320) void blur_hw(const __half2* __restrict__ ws,
                                               float2* __restrict__ out,
                                               const float* __restrict__ sigma) {
    __shared__ __align__(16) unsigned char smem[SMEM_BYTES];   // 27,520 B union
    __half2* slab = (__half2*)smem;            // phase 1: fp16 slab [SLABR][R2]
    float2*  hb   = (float2*)smem;             // phase 2: f32 hbuf [TB][HBS]

    const int tid  = threadIdx.x;
    const int bx   = blockIdx.x;
    const int tile = bx & 7;                 // 8 h-tiles of 20 rows
    const int d    = (bx >> 3) % DD;
    const int b    = bx / (8 * DD);
    const int h0   = tile * TB;

    float wh[WSZ];
    make_weights(sigma[b * 3 + 1], wh);

    // ---- stage slab rows h0-6 .. h0+25 (32 x 160 half2) raw fp16: 4 f4/thread ----
    const float4* p4 = (const float4*)(ws + b * N2 + d * P2);   // 40 f4 per fp16 row
    float4* l4 = (float4*)smem;
#pragma unroll
    for (int j = 0; j < 4; ++j) {
        const int f = j * 320 + tid;                   // 0..1279
        const int r = f / 40, q = f % 40;
        const int hh = h0 - 6 + r;
        float4 v = make_float4(0.f, 0.f, 0.f, 0.f);
        if (hh >= 0 && hh < HH) v = p4[hh * 40 + q];
        l4[f] = v;
    }
    __syncthreads();

    // ---- H-blur: one column-walk per thread (cvt fp16->f32 at read) ----
    float2 o[10];
    {
        const int w  = tid % 160;
        const int r0 = (tid / 160) * 10;
        float2 win[WSZ];
#pragma unroll
        for (int k = 0; k < WSZ - 1; ++k) win[k] = __half22float2(slab[(r0 + k) * R2 + w]);
#pragma unroll
        for (int i = 0; i < 10; ++i) {
            win[WSZ - 1] = __half22float2(slab[(r0 + i + WSZ - 1) * R2 + w]);
            float ax = 0.0f, ay = 0.0f;
#pragma unroll
            for (int k = 0; k < WSZ; ++k) { ax += wh[k] * win[k].x; ay += wh[k] * win[k].y; }
            o[i] = make_float2(ax, ay);
#pragma unroll
            for (int k = 0; k < WSZ - 1; ++k) win[k] = win[k + 1];
        }
    }
    __syncthreads();   // all slab reads done; reuse LDS as f32 hbuf[20][172]

    // ---- write hbuf (f32): zero stripes + data shifted +6 ----
    if (tid < 240) {
        const int r = tid / 12, c = tid % 12;
        const int col = (c < 6) ? c : (160 + c);
        hb[r * HBS + col] = make_float2(0.0f, 0.0f);
    }
    {
        const int w  = tid % 160;
        const int r0 = (tid / 160) * 10;
#pragma unroll
        for (int i = 0; i < 10; ++i) hb[(r0 + i) * HBS + 6 + w] = o[i];
    }
    __syncthreads();

    // ---- W-blur: 3200 outputs, pure f32 FMA, coalesced NONTEMPORAL stores ----
    float ww[WSZ];
    make_weights(sigma[b * 3 + 2], ww);

    nfloat2* oplane = (nfloat2*)(out + b * N2 + d * P2 + h0 * R2);
#pragma unroll
    for (int j = 0; j < 10; ++j) {
        const int oidx = j * 320 + tid;
        const int r = oidx / 160, w = oidx % 160;
        const float2* src = &hb[r * HBS + w];
        float ax = 0.0f, ay = 0.0f;
#pragma unroll
        for (int k = 0; k < WSZ; ++k) { const float2 v = src[k]; ax += ww[k] * v.x; ay += ww[k] * v.y; }
        nfloat2 res; res.x = ax; res.y = ay;
        __builtin_nontemporal_store(res, &oplane[oidx]);
    }
}

extern "C" void kernel_launch(void* const* d_in, const int* in_sizes, int n_in,
                              void* d_out, int out_size, void* d_ws, size_t ws_size,
                              hipStream_t stream) {
    const float2* img   = (const float2*)d_in[0];
    const float*  sigma = (const float*)d_in[1];
    float2*  out = (float2*)d_out;
    __half2* ws  = (__half2*)d_ws;

    blur_d<<<dim3(NCOL4 / 256, NSEGA), dim3(256), 0, stream>>>(img, ws, sigma);
    blur_hw<<<dim3(BB * DD * 8), dim3(320), 0, stream>>>(ws, out, sigma);
}

// Round 20
// 81.570 us; speedup vs baseline: 1.1151x; 1.1151x over previous
//
#include <hip/hip_runtime.h>
#include <hip/hip_fp16.h>

// DynamicGaussianBlur: [B=4, D=160, H=160, W=160, C=2] fp32, sigma [4,3],
// separable 3D gaussian, window 13 (radius 6), SAME zero padding.
// FINAL (= round-18 best, 81.9 us). Two passes; ws is FP16 (half2 = ch pair):
//   A: D-blur register line-walk, float4-wide, depth-8 register prefetch
//      queue; normal (caching) input loads — input stays partially
//      L3-resident across replays (r19 proved nt-loads cost ~9 us).
//                                                        in -> ws(fp16)
//   B: fused H+W blur per (b,d,h-tile); UNION LDS: fp16 slab (20,480 B)
//      for staging+H-blur, reused as f32 hbuf (27,520 B) for W-blur
//      (5 blocks/CU). OUT stores nontemporal.            ws -> out

#define WSZ 13
#define RAD 6
#define SEGA 40       // pass A: d-segment per thread (5 chunks of 8)
#define NSEGA 4
#define CHK 8         // chunk size = prefetch depth

typedef float nfloat2 __attribute__((ext_vector_type(2)));   // nt-capable float2

constexpr int BB = 4, DD = 160, HH = 160, WW = 160;
constexpr int R2 = 160;             // row in float2 / half2 units
constexpr int P2 = HH * WW;         // plane (25,600)
constexpr int N2 = DD * P2;         // batch volume
constexpr int P4 = P2 / 2;          // plane in float4 / uint2 units (12,800)
constexpr int N4 = N2 / 2;
constexpr int NCOL4 = BB * P4;      // pass-A float4 columns (51,200)

// Pass B tile
#define TB 20
#define SLABR (TB + 12)              // 32 slab rows (fp16: 20,480 B)
#define HBS 172                      // hbuf row stride (float2 units)
#define SMEM_BYTES (TB * HBS * 8)    // 27,520 B (f32 hbuf is the max)

__device__ __forceinline__ void make_weights(float sig, float* w) {
    const float invd = 1.0f / (2.0f * sig * sig + 1e-7f);
    float s = 0.0f;
#pragma unroll
    for (int k = 0; k < WSZ; ++k) {
        const float loc = (float)(k - RAD);
        w[k] = __expf(-loc * loc * invd);
        s += w[k];
    }
    const float inv = 1.0f / s;
#pragma unroll
    for (int k = 0; k < WSZ; ++k) w[k] *= inv;
}

__device__ __forceinline__ float4 ldq(const float4* __restrict__ p, int ibase, int q) {
    float4 v = make_float4(0.f, 0.f, 0.f, 0.f);
    if (q >= 0 && q < DD) v = p[ibase + q * P4];
    return v;
}

// ---------------- Pass A: D-blur walker with depth-8 register prefetch ----------------
__global__ __launch_bounds__(256) void blur_d(const float2* __restrict__ in,
                                              __half2* __restrict__ ws,
                                              const float* __restrict__ sigma) {
    const float4* in4 = (const float4*)in;
    uint2* wsU = (uint2*)ws;

    const int cid = blockIdx.x * 256 + threadIdx.x;   // float4-column id
    const int b   = cid / P4;                         // uniform per block
    const int rem = cid % P4;

    float wgt[WSZ];
    make_weights(sigma[b * 3 + 0], wgt);

    const int ibase = b * N4 + rem;                   // float4 index at d=0
    const int obase = b * N4 + rem;                   // uint2 index at d=0
    const int p0 = blockIdx.y * SEGA;

    // win[0..12] = q = p0-7 .. p0+5  (win[0] is dropped before first use)
    float4 win[WSZ];
    win[0] = make_float4(0.f, 0.f, 0.f, 0.f);
#pragma unroll
    for (int k = 1; k < WSZ; ++k) win[k] = ldq(in4, ibase, p0 - 7 + k);

    // nxt[0..7] = q = p0+6 .. p0+13
    float4 nxt[CHK];
#pragma unroll
    for (int j = 0; j < CHK; ++j) nxt[j] = ldq(in4, ibase, p0 + 6 + j);

#pragma unroll
    for (int t = 0; t < SEGA / CHK; ++t) {            // 5 chunks
        const int i0 = p0 + t * CHK;

        // issue next chunk's slide-in loads early: q = i0+14 .. i0+21
        float4 fut[CHK];
        if (t + 1 < SEGA / CHK) {
#pragma unroll
            for (int j = 0; j < CHK; ++j) fut[j] = ldq(in4, ibase, i0 + 14 + j);
        }

        // compute 8 outputs from win + nxt (loads issued one chunk ago)
#pragma unroll
        for (int j = 0; j < CHK; ++j) {
#pragma unroll
            for (int k = 0; k < WSZ - 1; ++k) win[k] = win[k + 1];
            win[WSZ - 1] = nxt[j];

            float a0 = 0.f, a1 = 0.f, a2 = 0.f, a3 = 0.f;
#pragma unroll
            for (int k = 0; k < WSZ; ++k) {
                const float4 v = win[k];
                a0 += wgt[k] * v.x; a1 += wgt[k] * v.y;
                a2 += wgt[k] * v.z; a3 += wgt[k] * v.w;
            }
            union { uint2 u; __half2 h[2]; } o;
            o.h[0] = __float22half2_rn(make_float2(a0, a1));
            o.h[1] = __float22half2_rn(make_float2(a2, a3));
            wsU[obase + (i0 + j) * P4] = o.u;         // normal store: keep ws in L3
        }

        if (t + 1 < SEGA / CHK) {
#pragma unroll
            for (int j = 0; j < CHK; ++j) nxt[j] = fut[j];
        }
    }
}

// ---------------- Pass B: fused H+W blur, union LDS, one (b,d,h-tile) per block ----------------
__global__ __launch_bounds__(320) void blur_hw(const __half2* __restrict__ ws,
                                               float2* __restrict__ out,
                                               const float* __restrict__ sigma) {
    __shared__ __align__(16) unsigned char smem[SMEM_BYTES];   // 27,520 B union
    __half2* slab = (__half2*)smem;            // phase 1: fp16 slab [SLABR][R2]
    float2*  hb   = (float2*)smem;             // phase 2: f32 hbuf [TB][HBS]

    const int tid  = threadIdx.x;
    const int bx   = blockIdx.x;
    const int tile = bx & 7;                 // 8 h-tiles of 20 rows
    const int d    = (bx >> 3) % DD;
    const int b    = bx / (8 * DD);
    const int h0   = tile * TB;

    float wh[WSZ];
    make_weights(sigma[b * 3 + 1], wh);

    // ---- stage slab rows h0-6 .. h0+25 (32 x 160 half2) raw fp16: 4 f4/thread ----
    const float4* p4 = (const float4*)(ws + b * N2 + d * P2);   // 40 f4 per fp16 row
    float4* l4 = (float4*)smem;
#pragma unroll
    for (int j = 0; j < 4; ++j) {
        const int f = j * 320 + tid;                   // 0..1279
        const int r = f / 40, q = f % 40;
        const int hh = h0 - 6 + r;
        float4 v = make_float4(0.f, 0.f, 0.f, 0.f);
        if (hh >= 0 && hh < HH) v = p4[hh * 40 + q];
        l4[f] = v;
    }
    __syncthreads();

    // ---- H-blur: one column-walk per thread (cvt fp16->f32 at read) ----
    float2 o[10];
    {
        const int w  = tid % 160;
        const int r0 = (tid / 160) * 10;
        float2 win[WSZ];
#pragma unroll
        for (int k = 0; k < WSZ - 1; ++k) win[k] = __half22float2(slab[(r0 + k) * R2 + w]);
#pragma unroll
        for (int i = 0; i < 10; ++i) {
            win[WSZ - 1] = __half22float2(slab[(r0 + i + WSZ - 1) * R2 + w]);
            float ax = 0.0f, ay = 0.0f;
#pragma unroll
            for (int k = 0; k < WSZ; ++k) { ax += wh[k] * win[k].x; ay += wh[k] * win[k].y; }
            o[i] = make_float2(ax, ay);
#pragma unroll
            for (int k = 0; k < WSZ - 1; ++k) win[k] = win[k + 1];
        }
    }
    __syncthreads();   // all slab reads done; reuse LDS as f32 hbuf[20][172]

    // ---- write hbuf (f32): zero stripes + data shifted +6 ----
    if (tid < 240) {
        const int r = tid / 12, c = tid % 12;
        const int col = (c < 6) ? c : (160 + c);
        hb[r * HBS + col] = make_float2(0.0f, 0.0f);
    }
    {
        const int w  = tid % 160;
        const int r0 = (tid / 160) * 10;
#pragma unroll
        for (int i = 0; i < 10; ++i) hb[(r0 + i) * HBS + 6 + w] = o[i];
    }
    __syncthreads();

    // ---- W-blur: 3200 outputs, pure f32 FMA, coalesced NONTEMPORAL stores ----
    float ww[WSZ];
    make_weights(sigma[b * 3 + 2], ww);

    nfloat2* oplane = (nfloat2*)(out + b * N2 + d * P2 + h0 * R2);
#pragma unroll
    for (int j = 0; j < 10; ++j) {
        const int oidx = j * 320 + tid;
        const int r = oidx / 160, w = oidx % 160;
        const float2* src = &hb[r * HBS + w];
        float ax = 0.0f, ay = 0.0f;
#pragma unroll
        for (int k = 0; k < WSZ; ++k) { const float2 v = src[k]; ax += ww[k] * v.x; ay += ww[k] * v.y; }
        nfloat2 res; res.x = ax; res.y = ay;
        __builtin_nontemporal_store(res, &oplane[oidx]);
    }
}

extern "C" void kernel_launch(void* const* d_in, const int* in_sizes, int n_in,
                              void* d_out, int out_size, void* d_ws, size_t ws_size,
                              hipStream_t stream) {
    const float2* img   = (const float2*)d_in[0];
    const float*  sigma = (const float*)d_in[1];
    float2*  out = (float2*)d_out;
    __half2* ws  = (__half2*)d_ws;

    blur_d<<<dim3(NCOL4 / 256, NSEGA), dim3(256), 0, stream>>>(img, ws, sigma);
    blur_hw<<<dim3(BB * DD * 8), dim3(320), 0, stream>>>(ws, out, sigma);
}